// Round 13
// baseline (200.134 us; speedup 1.0000x reference)
//
#include <hip/hip_runtime.h>
#include <math.h>

// fp16-MFMA fused MHA-like layer (fp32 accumulate), round 15:
//  - R15: qkv converts x fp32->f16 on the fly (reg-staged A: 2x
//    global_load_dwordx4 issued early, cvt, ds_write_b128 to swizzled slot;
//    B keeps global_load_lds). Eliminates prep's x round-trip (48 MB BW
//    ~7.6us). prep is now W-transpose only (1024 blocks). Bit-identical
//    conversion (RNE) -> absmax unchanged.
//  - R14: pv z=0 descending / z=1 ascending strips -> per-CU kend sum const.
//  - mid: static-528 (3 integer rounds = optimum for 528 tiles; balance
//    direction closed).
//  - R10: softmax traffic trim (load j<=i, store j<kend only).
//  - gemm_acc: double-buffered LDS, ONE barrier per K-step, BK=32.
//  - Swizzle: stage src chunk (l&3)^((l>>3)&3), read slot quad^((row>>1)&3).
//  - 5 dispatches: prep(W), QKV, mid (QK^T || V@Wo), softmax, PV->out

typedef _Float16 f16x8 __attribute__((ext_vector_type(8)));
typedef float f32x4 __attribute__((ext_vector_type(4)));

#define BK 32   // halves per LDS row (64 B)

__device__ __forceinline__ void gload_lds16(const void* g, void* l) {
  __builtin_amdgcn_global_load_lds(
      (const __attribute__((address_space(1))) void*)g,
      (__attribute__((address_space(3))) void*)l, 16, 0, 0);
}

// Accumulate C-tile (m0,n0) of A[*,sAr] @ BT[*,sBr]^T over k < kend.
// Ah/Bh are double buffers: 2 * TMp*BK / 2 * TNp*BK halves.
// LDS: [row][chunk] chunks of 8 halves (16B); logical chunk c of row r at
// physical slot c ^ ((r>>1)&3). Staging swizzles the global source side
// (global_load_lds LDS dest must stay lane-linear); ds_read mirrors it.
template<int TMp, int TNp>
__device__ __forceinline__ void gemm_acc(
    const _Float16* __restrict__ A, const _Float16* __restrict__ BT,
    _Float16* Ah, _Float16* Bh, int sAr, int sBr, int kend, int m0, int n0,
    f32x4 (&acc)[TMp / 32][TNp / 32])
{
  const int tid  = threadIdx.x;
  const int lane = tid & 63;
  const int wid  = tid >> 6;
  const int wm   = (wid >> 1) * (TMp / 2);
  const int wn   = (wid & 1) * (TNp / 2);
  const int l15  = lane & 15;
  const int quad = lane >> 4;
  constexpr int MT = TMp / 32;
  constexpr int NT = TNp / 32;
  constexpr int AI = TMp / 64;            // staging instrs per wave (16 rows)
  constexpr int BI = TNp / 64;
  const int r16 = lane >> 2;              // row within 16-row group
  const int swc = ((lane & 3) ^ ((lane >> 3) & 3)) * 8;  // swizzled src chunk
  const int arow = wid * (TMp / 4);
  const int brow = wid * (TNp / 4);

  auto stage = [&](int k0, int buf) {
    _Float16* Ad = Ah + buf * (TMp * BK);
    _Float16* Bd = Bh + buf * (TNp * BK);
    #pragma unroll
    for (int t = 0; t < AI; ++t)
      gload_lds16(A + (long long)(m0 + arow + t * 16 + r16) * sAr + k0 + swc,
                  Ad + (arow + t * 16) * BK);
    #pragma unroll
    for (int t = 0; t < BI; ++t)
      gload_lds16(BT + (long long)(n0 + brow + t * 16 + r16) * sBr + k0 + swc,
                  Bd + (brow + t * 16) * BK);
  };

  stage(0, 0);
  __syncthreads();                        // drain vmcnt(0) for step 0
  int cur = 0;
  for (int k0 = 0; k0 < kend; k0 += BK) {
    if (k0 + BK < kend) stage(k0 + BK, cur ^ 1);   // prefetch next step

    const int ch = (quad ^ ((l15 >> 1) & 3)) * 8;  // swizzled read slot
    const _Float16* ab = Ah + cur * (TMp * BK) + (wm + l15) * BK + ch;
    const _Float16* bb = Bh + cur * (TNp * BK) + (wn + l15) * BK + ch;
    f16x8 af[MT], bf[NT];
    #pragma unroll
    for (int t = 0; t < MT; ++t) af[t] = *(const f16x8*)(ab + t * 16 * BK);
    #pragma unroll
    for (int t = 0; t < NT; ++t) bf[t] = *(const f16x8*)(bb + t * 16 * BK);
    #pragma unroll
    for (int mt = 0; mt < MT; ++mt)
      #pragma unroll
      for (int nt = 0; nt < NT; ++nt)
        acc[mt][nt] = __builtin_amdgcn_mfma_f32_16x16x32_f16(
            af[mt], bf[nt], acc[mt][nt], 0, 0, 0);

    __syncthreads();   // one barrier/step: drains prefetch vmcnt + syncs reads
    cur ^= 1;
  }
}

// qkv variant: A is fp32 (x), reg-staged with on-the-fly f16 conversion:
// issue 2x global_load_dwordx4 per t early, cvt+ds_write AFTER the MFMAs
// (loads hide under compute), barrier syncs the writes. B via gload_lds.
// A dest swizzle applied on the ds_write side (phys chunk = c ^ ((r>>1)&3)).
__device__ __forceinline__ void gemm_acc_cvtA(
    const float* __restrict__ A, const _Float16* __restrict__ BT,
    _Float16* Ah, _Float16* Bh, int sAr, int sBr, int kend, int m0, int n0,
    f32x4 (&acc)[4][4])
{
  const int tid  = threadIdx.x;
  const int lane = tid & 63;
  const int wid  = tid >> 6;
  const int wm   = (wid >> 1) * 64;
  const int wn   = (wid & 1) * 64;
  const int l15  = lane & 15;
  const int quad = lane >> 4;
  const int r16  = lane >> 2;             // row within 16-row group
  const int chnk = lane & 3;              // logical chunk (8 floats)
  const int swc  = (chnk ^ ((lane >> 3) & 3)) * 8;  // B-side src swizzle
  const int arow = wid * 32;
  const int brow = wid * 32;

  float4 a0[2], a1[2];
  auto loadA = [&](int k0) {
    #pragma unroll
    for (int t = 0; t < 2; ++t) {
      const float* p =
          A + (long long)(m0 + arow + t * 16 + r16) * sAr + k0 + chnk * 8;
      a0[t] = *(const float4*)p;
      a1[t] = *(const float4*)(p + 4);
    }
  };
  auto writeA = [&](int buf) {
    _Float16* Ad = Ah + buf * (128 * BK);
    #pragma unroll
    for (int t = 0; t < 2; ++t) {
      const int r  = arow + t * 16 + r16;
      const int pc = chnk ^ ((r >> 1) & 3);
      f16x8 h = {(_Float16)a0[t].x, (_Float16)a0[t].y,
                 (_Float16)a0[t].z, (_Float16)a0[t].w,
                 (_Float16)a1[t].x, (_Float16)a1[t].y,
                 (_Float16)a1[t].z, (_Float16)a1[t].w};
      *(f16x8*)(Ad + r * BK + pc * 8) = h;
    }
  };
  auto stageB = [&](int k0, int buf) {
    _Float16* Bd = Bh + buf * (128 * BK);
    #pragma unroll
    for (int t = 0; t < 2; ++t)
      gload_lds16(BT + (long long)(n0 + brow + t * 16 + r16) * sBr + k0 + swc,
                  Bd + (brow + t * 16) * BK);
  };

  loadA(0);
  stageB(0, 0);
  writeA(0);
  __syncthreads();                        // drains B vmcnt + A ds_writes
  int cur = 0;
  for (int k0 = 0; k0 < kend; k0 += BK) {
    const bool nxt = (k0 + BK < kend);
    if (nxt) { loadA(k0 + BK); stageB(k0 + BK, cur ^ 1); }

    const int ch = (quad ^ ((l15 >> 1) & 3)) * 8;
    const _Float16* ab = Ah + cur * (128 * BK) + (wm + l15) * BK + ch;
    const _Float16* bb = Bh + cur * (128 * BK) + (wn + l15) * BK + ch;
    f16x8 af[4], bf[4];
    #pragma unroll
    for (int t = 0; t < 4; ++t) af[t] = *(const f16x8*)(ab + t * 16 * BK);
    #pragma unroll
    for (int t = 0; t < 4; ++t) bf[t] = *(const f16x8*)(bb + t * 16 * BK);
    #pragma unroll
    for (int mt = 0; mt < 4; ++mt)
      #pragma unroll
      for (int nt = 0; nt < 4; ++nt)
        acc[mt][nt] = __builtin_amdgcn_mfma_f32_16x16x32_f16(
            af[mt], bf[nt], acc[mt][nt], 0, 0, 0);

    if (nxt) writeA(cur ^ 1);   // disjoint buffer; barrier below syncs it
    __syncthreads();
    cur ^= 1;
  }
}

// Epilogue. C/D layout: col = lane&15, row = quad*4 + reg (HW-verified).
template<int TMp, int TNp, bool RELU, bool HAS_BIAS, typename OT>
__device__ __forceinline__ void gemm_store(
    f32x4 (&acc)[TMp / 32][TNp / 32], const float* __restrict__ bias,
    OT* __restrict__ C, int Nout, float scale, int m0, int n0)
{
  const int tid  = threadIdx.x;
  const int lane = tid & 63;
  const int wid  = tid >> 6;
  const int wm   = (wid >> 1) * (TMp / 2);
  const int wn   = (wid & 1) * (TNp / 2);
  const int l15  = lane & 15;
  const int quad = lane >> 4;
  constexpr int MT = TMp / 32;
  constexpr int NT = TNp / 32;

  float bvals[NT];
  if (HAS_BIAS) {
    #pragma unroll
    for (int nt = 0; nt < NT; ++nt)
      bvals[nt] = bias[n0 + wn + nt * 16 + l15];
  }
  #pragma unroll
  for (int mt = 0; mt < MT; ++mt) {
    #pragma unroll
    for (int nt = 0; nt < NT; ++nt) {
      const int col = n0 + wn + nt * 16 + l15;
      #pragma unroll
      for (int r = 0; r < 4; ++r) {
        const int row = m0 + wm + mt * 16 + quad * 4 + r;
        float v = acc[mt][nt][r] * scale;
        if (HAS_BIAS) v += bvals[nt];
        if (RELU) v = fmaxf(v, 0.f);
        C[(long long)row * Nout + col] = (OT)v;
      }
    }
  }
}

// fused QKV: relu(x @ W{q,k,v} + b) -> f16; Wcat = [Wq^T;Wk^T;Wv^T;Wo^T]
// A = x fp32, converted on the fly (R15).
__global__ __launch_bounds__(256) void qkv_kernel(
    const float* __restrict__ x, const _Float16* __restrict__ Wcat,
    const float* __restrict__ bq, const float* __restrict__ bk,
    const float* __restrict__ bv,
    _Float16* __restrict__ Qh, _Float16* __restrict__ Kh,
    _Float16* __restrict__ Vh, int D)
{
  __shared__ _Float16 Ah[2 * 128 * BK];
  __shared__ _Float16 Bh[2 * 128 * BK];
  const int m0  = blockIdx.y * 128;
  const int n0g = blockIdx.x * 128;       // 0..3071
  f32x4 acc[4][4];
  #pragma unroll
  for (int i = 0; i < 4; ++i)
    #pragma unroll
    for (int j = 0; j < 4; ++j) acc[i][j] = (f32x4){0.f, 0.f, 0.f, 0.f};

  gemm_acc_cvtA(x, Wcat, Ah, Bh, D, D, D, m0, n0g, acc);

  const int mat = n0g >> 10;              // D = 1024
  const int c0  = n0g & 1023;
  _Float16* C = (mat == 0) ? Qh : (mat == 1) ? Kh : Vh;
  const float* bias = (mat == 0) ? bq : (mat == 1) ? bk : bv;
  gemm_store<128, 128, true, true, _Float16>(acc, bias, C, D, 1.0f, m0, c0);
}

// mid: blocks 0..271 -> E = QK^T/32 (packed triangular, 128x128 tiles);
//      blocks 272..527 -> VWT = (V@Wo)^T (A = Wo^T, BT = V), 128x128 tiles.
// Diagonal QK^T tiles compute a garbage upper half; softmax zeroes the
// region pv reads (j < kend) and pv never reads past kend.
__global__ __launch_bounds__(256) void mid_kernel(
    const _Float16* __restrict__ Qh, const _Float16* __restrict__ Kh,
    _Float16* __restrict__ E, const _Float16* __restrict__ WoT,
    const _Float16* __restrict__ Vh, _Float16* __restrict__ VWT,
    int S, int D)
{
  __shared__ _Float16 Ah[2 * 128 * BK];
  __shared__ _Float16 Bh[2 * 128 * BK];
  const _Float16 *A, *BT;
  _Float16* C;
  int m0, n0;
  float scale;
  const int id = blockIdx.x;
  if (id < 272) {                          // QK^T, 136 tiles per batch
    const int z = (id >= 136);
    const int t = id - z * 136;
    int i = (int)((sqrtf(8.f * t + 1.f) - 1.f) * 0.5f);
    while ((i + 1) * (i + 2) / 2 <= t) ++i;
    while (i * (i + 1) / 2 > t) --i;
    const int j = t - i * (i + 1) / 2;     // 0..i
    m0 = i * 128;
    n0 = j * 128;
    A  = Qh + (long long)z * S * D;
    BT = Kh + (long long)z * S * D;
    C  = E + (long long)z * S * S;
    scale = 0.03125f;
  } else {                                 // V @ Wo, 128 tiles per batch
    const int t = id - 272;
    const int z = t >> 7;
    const int u = t & 127;
    m0 = (u >> 4) * 128;                   // D rows of Wo^T
    n0 = (u & 15) * 128;                   // S cols (V rows)
    A  = WoT;
    BT = Vh + (long long)z * S * D;
    C  = VWT + (long long)z * D * S;
    scale = 1.0f;
  }
  f32x4 acc[4][4];
  #pragma unroll
  for (int i = 0; i < 4; ++i)
    #pragma unroll
    for (int j = 0; j < 4; ++j) acc[i][j] = (f32x4){0.f, 0.f, 0.f, 0.f};

  gemm_acc<128, 128>(A, BT, Ah, Bh, D, D, D, m0, n0, acc);
  gemm_store<128, 128, false, false, _Float16>(acc, nullptr, C, S, scale,
                                               m0, n0);
}

// out = relu(P @ VW + bo) -> fp32; kend = m0+64 (causal cap).
// R14 balance: round-robin pairs CU c with blocks (z=0,y) and (z=1,y);
// z=0 strips descending, z=1 ascending -> per-CU kend sum = 2112 const.
__global__ __launch_bounds__(256) void pv_kernel(
    const _Float16* __restrict__ E, const _Float16* __restrict__ VWT,
    const float* __restrict__ bo, float* __restrict__ out, int S, int D)
{
  __shared__ _Float16 Ah[2 * 64 * BK];
  __shared__ _Float16 Bh[2 * 128 * BK];
  const int z  = blockIdx.z;
  const int gy = (int)gridDim.y;
  const int m0 = ((z == 0) ? (gy - 1 - (int)blockIdx.y) : (int)blockIdx.y) * 64;
  const int n0 = blockIdx.x * 128;
  const _Float16* A  = E + (long long)z * S * S;
  const _Float16* BT = VWT + (long long)z * D * S;
  float* C = out + (long long)z * S * D;
  const int kend = m0 + 64;

  f32x4 acc[2][4];
  #pragma unroll
  for (int i = 0; i < 2; ++i)
    #pragma unroll
    for (int j = 0; j < 4; ++j) acc[i][j] = (f32x4){0.f, 0.f, 0.f, 0.f};

  gemm_acc<64, 128>(A, BT, Ah, Bh, S, S, kend, m0, n0, acc);
  gemm_store<64, 128, true, true, float>(acc, bo, C, D, 1.0f, m0, n0);
}

// prep (R15: W transpose+convert only): 1024 blocks = 4 mats x 256 tiles
// of 64x64 into Wcat = [Wq^T;Wk^T;Wv^T;Wo^T].
__global__ __launch_bounds__(256) void prep_kernel(
    const float* __restrict__ W0, const float* __restrict__ W1,
    const float* __restrict__ W2, const float* __restrict__ W3,
    _Float16* __restrict__ Wcat, int D)
{
  const int tid = threadIdx.x;
  __shared__ _Float16 t[64][72];
  const int u = blockIdx.x;
  const int z = u >> 8;
  const int v = u & 255;
  const float* W = (z == 0) ? W0 : (z == 1) ? W1 : (z == 2) ? W2 : W3;
  _Float16* dst = Wcat + (long long)z * D * D;
  const int k0 = (v >> 4) * 64, n0 = (v & 15) * 64;
  #pragma unroll
  for (int it = 0; it < 4; ++it) {
    int idx = tid + it * 256;
    int r = idx >> 4, c4 = (idx & 15) << 2;
    float4 w = *(const float4*)(W + (long long)(k0 + r) * D + n0 + c4);
    t[r][c4 + 0] = (_Float16)w.x; t[r][c4 + 1] = (_Float16)w.y;
    t[r][c4 + 2] = (_Float16)w.z; t[r][c4 + 3] = (_Float16)w.w;
  }
  __syncthreads();
  #pragma unroll
  for (int it = 0; it < 2; ++it) {
    int idx = tid + it * 256;
    int r = idx >> 3, c8 = (idx & 7) << 3;
    f16x8 o;
    #pragma unroll
    for (int j = 0; j < 8; ++j) o[j] = t[c8 + j][r];
    *(f16x8*)(dst + (long long)(n0 + r) * D + k0 + c8) = o;
  }
}

// in-place causal softmax, fp32 math, f16 IO; zeros for j > i.
// Load only j0 < n (rest contribute -inf/0 to the reductions);
// store only j0 < kend=(i&~63)+64 -- pv's K-loop never reads past kend,
// so raw mid garbage may remain at j >= kend. No early returns: every
// thread reaches both __syncthreads.
__global__ __launch_bounds__(256) void softmax_causal_h(
    _Float16* __restrict__ E, int S)
{
  const int i = blockIdx.x;
  _Float16* row = E + ((long long)blockIdx.y * S + i) * S;
  const int tid = threadIdx.x;
  const int n = i + 1;
  const int kend = (i & ~63) + 64;
  const int j0 = tid * 8;

  f16x8 hv;
  const bool has = (j0 < n);
  if (has) hv = *(const f16x8*)(row + j0);
  float vals[8];
  float m = -3.0e38f;
  #pragma unroll
  for (int t = 0; t < 8; ++t) {
    float v = (has && j0 + t < n) ? (float)hv[t] : -3.0e38f;
    vals[t] = v;
    m = fmaxf(m, v);
  }
  #pragma unroll
  for (int o = 32; o > 0; o >>= 1) m = fmaxf(m, __shfl_down(m, o, 64));

  __shared__ float rmax[4];
  __shared__ float rsum[4];
  const int wave = tid >> 6;
  if ((tid & 63) == 0) rmax[wave] = m;
  __syncthreads();
  m = fmaxf(fmaxf(rmax[0], rmax[1]), fmaxf(rmax[2], rmax[3]));

  float s = 0.f;
  #pragma unroll
  for (int t = 0; t < 8; ++t) {
    float e = (has && j0 + t < n) ? expf(vals[t] - m) : 0.f;
    vals[t] = e;
    s += e;
  }
  #pragma unroll
  for (int o = 32; o > 0; o >>= 1) s += __shfl_down(s, o, 64);
  if ((tid & 63) == 0) rsum[wave] = s;
  __syncthreads();
  s = rsum[0] + rsum[1] + rsum[2] + rsum[3];

  if (j0 < kend) {
    const float inv = 1.0f / s;
    f16x8 ov;
    #pragma unroll
    for (int t = 0; t < 8; ++t) ov[t] = (_Float16)(vals[t] * inv);
    *(f16x8*)(row + j0) = ov;
  }
}

extern "C" void kernel_launch(void* const* d_in, const int* in_sizes, int n_in,
                              void* d_out, int out_size, void* d_ws, size_t ws_size,
                              hipStream_t stream) {
  const float* x  = (const float*)d_in[0];
  const float* Wq = (const float*)d_in[1];
  const float* bq = (const float*)d_in[2];
  const float* Wk = (const float*)d_in[3];
  const float* bk = (const float*)d_in[4];
  const float* Wv = (const float*)d_in[5];
  const float* bv = (const float*)d_in[6];
  const float* Wo = (const float*)d_in[7];
  const float* bo = (const float*)d_in[8];
  float* out = (float*)d_out;

  const int Bn = 2, S = 2048, D = 1024;
  const int M = Bn * S;                       // 4096
  const size_t MD = (size_t)M * D;            // 4M elems
  const size_t DD = (size_t)D * D;            // 1M
  const size_t SS = (size_t)Bn * S * S;       // 8M

  _Float16* ws   = (_Float16*)d_ws;
  _Float16* Wcat = ws + MD;            // 4*DD (xh slot retired, offsets kept)
  _Float16* Qh   = Wcat + 4 * DD;      // MD
  _Float16* Kh   = Qh + MD;            // MD
  _Float16* Vh   = Kh + MD;            // MD
  _Float16* VWT  = Vh + MD;            // MD  ((V@Wo)^T, [D,S] per batch)
  _Float16* E    = VWT + MD;           // SS

  dim3 blk(256);

  prep_kernel<<<dim3(1024), blk, 0, stream>>>(Wq, Wk, Wv, Wo, Wcat, D);

  qkv_kernel<<<dim3(3 * D / 128, M / 128), blk, 0, stream>>>(
      x, Wcat, bq, bk, bv, Qh, Kh, Vh, D);

  mid_kernel<<<dim3(528), blk, 0, stream>>>(
      Qh, Kh, E, Wcat + 3 * DD, Vh, VWT, S, D);

  softmax_causal_h<<<dim3(S, Bn), blk, 0, stream>>>(E, S);

  pv_kernel<<<dim3(D / 128, S / 64, Bn), blk, 0, stream>>>(
      E, VWT, bo, out, S, D);
}